// Round 1
// baseline (393.685 us; speedup 1.0000x reference)
//
#include <hip/hip_runtime.h>
#include <math.h>

#define NHEADS 16
#define HD 64
#define HID 1024
#define BATCH 4
#define SQ 16
#define SKV 8192
#define NCHUNK 16
#define CHUNK 512   // keys per block
#define TK 64       // keys per LDS tile
#define LN_EPS 1e-5f

// ---------------------------------------------------------------------------
// Kernel 1: q = RoPE(x @ wq^T + bq)  -> q_ws laid out [B][NH][SQ][HD]
// one block per (b,sq) row
// ---------------------------------------------------------------------------
__global__ __launch_bounds__(256) void qrope_kernel(
    const float* __restrict__ x,     // [B*SQ][HID]
    const float* __restrict__ xm,    // [B*SQ][HD]
    const float* __restrict__ wq,    // [HID][HID]
    const float* __restrict__ bq,    // [HID]
    float* __restrict__ qout)        // [B][NH][SQ][HD]
{
    __shared__ float xs[HID];
    __shared__ float qrow[HID];
    __shared__ float xms[HD];

    const int r = blockIdx.x;          // b*SQ + sq
    const int b = r >> 4, sq = r & 15;
    const int t = threadIdx.x;

    float4* xs4 = (float4*)xs;
    const float4* xg = (const float4*)(x + (size_t)r * HID);
    xs4[t] = xg[t];                    // 256 float4 = 1024 floats
    if (t < 16) ((float4*)xms)[t] = ((const float4*)(xm + (size_t)r * HD))[t];
    __syncthreads();

    #pragma unroll
    for (int p = 0; p < 4; ++p) {
        const int j = t + p * 256;
        float a = bq[j];
        const float4* wr = (const float4*)(wq + (size_t)j * HID);
        #pragma unroll 8
        for (int i = 0; i < HID / 4; ++i) {
            float4 wv = wr[i];
            float4 xv = xs4[i];
            a += wv.x * xv.x + wv.y * xv.y + wv.z * xv.z + wv.w * xv.w;
        }
        qrow[j] = a;
    }
    __syncthreads();

    #pragma unroll
    for (int p = 0; p < 4; ++p) {
        const int j = t + p * 256;
        const int hh = j >> 6, dd = j & 63;
        float v;
        if (dd < 32) {
            // out = q0*cos - q1*sin ; sin = xm[0:32], cos = xm[32:64]
            v = qrow[hh * 64 + dd] * xms[32 + dd] - qrow[hh * 64 + dd + 32] * xms[dd];
        } else {
            const int d2 = dd - 32;
            v = qrow[hh * 64 + d2] * xms[d2] + qrow[hh * 64 + dd] * xms[32 + d2];
        }
        qout[(((size_t)b * NHEADS + hh) * SQ + sq) * HD + dd] = v;
    }
}

// ---------------------------------------------------------------------------
// Kernel 2: flash-style partial attention.
// grid (NCHUNK, NH, B), 256 threads (4 waves).
// wave w owns q rows 4w..4w+3; lane l owns key (within tile) and output dim l.
// ---------------------------------------------------------------------------
__global__ __launch_bounds__(256) void attn_partial(
    const float* __restrict__ q,     // [B][NH][SQ][HD]
    const float* __restrict__ kc,    // [B][NH][SKV][HD]
    const float* __restrict__ vc,    // [B][NH][SKV][HD]
    float* __restrict__ o_part,      // [B*NH][NCHUNK][SQ][HD]
    float* __restrict__ ml_part)     // [B*NH][NCHUNK][SQ][2]
{
    __shared__ float4 Ks[TK * 17];   // [64 keys][16 float4 + 1 pad f4] -> stride 68 floats
    __shared__ float4 Vs[TK * 17];
    __shared__ float4 qs[SQ * 16];   // [16 q rows][16 float4]
    __shared__ float4 ps[SQ * 16];   // p values, [16 q rows][64 floats]

    const int chunk = blockIdx.x, h = blockIdx.y, b = blockIdx.z;
    const int bh = b * NHEADS + h;
    const int t = threadIdx.x, w = t >> 6, l = t & 63;

    const float* qb = q + (size_t)bh * SQ * HD;
    const float* kb = kc + (size_t)bh * SKV * HD + (size_t)chunk * CHUNK * HD;
    const float* vb = vc + (size_t)bh * SKV * HD + (size_t)chunk * CHUNK * HD;

    qs[t] = ((const float4*)qb)[t];  // 256 float4 = full 16x64 q block

    float m[4], lsum[4], oacc[4];
    #pragma unroll
    for (int c = 0; c < 4; ++c) { m[c] = -INFINITY; lsum[c] = 0.f; oacc[c] = 0.f; }

    const float* Vsf = (const float*)Vs;
    float* psf = (float*)ps;

    for (int tile = 0; tile < CHUNK / TK; ++tile) {
        __syncthreads();  // protect Ks/Vs (and first-iter qs) from prior readers
        const float4* kg = (const float4*)(kb + (size_t)tile * TK * HD);
        const float4* vg = (const float4*)(vb + (size_t)tile * TK * HD);
        #pragma unroll
        for (int p = 0; p < 4; ++p) {
            const int idx = t + p * 256;        // 0..1023 float4s
            const int key = idx >> 4;
            const int j = idx & 15;
            Ks[key * 17 + j] = kg[idx];
            Vs[key * 17 + j] = vg[idx];
        }
        __syncthreads();

        // ---- scores: s[c] = q[4w+c] . K[key=l]
        float s[4] = {0.f, 0.f, 0.f, 0.f};
        #pragma unroll
        for (int j = 0; j < 16; ++j) {
            float4 kv = Ks[l * 17 + j];
            #pragma unroll
            for (int c = 0; c < 4; ++c) {
                float4 qv = qs[(4 * w + c) * 16 + j];
                s[c] += kv.x * qv.x + kv.y * qv.y + kv.z * qv.z + kv.w * qv.w;
            }
        }

        // ---- online softmax update (wave-wide reduce; rows are wave-local)
        #pragma unroll
        for (int c = 0; c < 4; ++c) {
            float mx = s[c];
            #pragma unroll
            for (int off = 32; off; off >>= 1) mx = fmaxf(mx, __shfl_xor(mx, off));
            const float mn = fmaxf(m[c], mx);
            const float p = __expf(s[c] - mn);
            float ssum = p;
            #pragma unroll
            for (int off = 32; off; off >>= 1) ssum += __shfl_xor(ssum, off);
            const float scale = __expf(m[c] - mn);
            lsum[c] = lsum[c] * scale + ssum;
            m[c] = mn;
            oacc[c] *= scale;
            psf[(4 * w + c) * 64 + l] = p;   // wave-local row, no block sync needed
        }

        // ---- PV: oacc[c] += sum_k p[4w+c][k] * V[k][d=l]
        #pragma unroll
        for (int kq = 0; kq < 16; ++kq) {
            const float v0 = Vsf[(kq * 4 + 0) * 68 + l];
            const float v1 = Vsf[(kq * 4 + 1) * 68 + l];
            const float v2 = Vsf[(kq * 4 + 2) * 68 + l];
            const float v3 = Vsf[(kq * 4 + 3) * 68 + l];
            #pragma unroll
            for (int c = 0; c < 4; ++c) {
                float4 pq = ps[(4 * w + c) * 16 + kq];
                oacc[c] += pq.x * v0 + pq.y * v1 + pq.z * v2 + pq.w * v3;
            }
        }
    }

    // ---- write partials
    #pragma unroll
    for (int c = 0; c < 4; ++c) {
        const int qi = 4 * w + c;
        o_part[(((size_t)bh * NCHUNK + chunk) * SQ + qi) * HD + l] = oacc[c];
    }
    if (l == 0) {
        #pragma unroll
        for (int c = 0; c < 4; ++c) {
            const int qi = 4 * w + c;
            ml_part[(((size_t)bh * NCHUNK + chunk) * SQ + qi) * 2 + 0] = m[c];
            ml_part[(((size_t)bh * NCHUNK + chunk) * SQ + qi) * 2 + 1] = lsum[c];
        }
    }
}

// ---------------------------------------------------------------------------
// Kernel 3: combine partials over chunks -> ctx [B][SQ][HID]
// one block per (b,h)
// ---------------------------------------------------------------------------
__global__ __launch_bounds__(256) void attn_combine(
    const float* __restrict__ o_part,
    const float* __restrict__ ml_part,
    float* __restrict__ ctx)
{
    __shared__ float mls[NCHUNK * SQ * 2];   // 512 floats
    const int bh = blockIdx.x;
    const int b = bh >> 4, h = bh & 15;
    const int t = threadIdx.x;

    mls[t] = ml_part[(size_t)bh * NCHUNK * SQ * 2 + t];
    mls[t + 256] = ml_part[(size_t)bh * NCHUNK * SQ * 2 + t + 256];
    __syncthreads();

    const int d = t & 63, qg = t >> 6;
    #pragma unroll
    for (int ii = 0; ii < 4; ++ii) {
        const int qi = qg * 4 + ii;
        float M = -INFINITY;
        #pragma unroll
        for (int c = 0; c < NCHUNK; ++c) M = fmaxf(M, mls[(c * SQ + qi) * 2]);
        float L = 0.f, O = 0.f;
        #pragma unroll
        for (int c = 0; c < NCHUNK; ++c) {
            const float sc = __expf(mls[(c * SQ + qi) * 2] - M);
            L += mls[(c * SQ + qi) * 2 + 1] * sc;
            O += o_part[(((size_t)bh * NCHUNK + c) * SQ + qi) * HD + d] * sc;
        }
        ctx[((size_t)b * SQ + qi) * HID + h * HD + d] = O / L;
    }
}

// ---------------------------------------------------------------------------
// Kernel 4: y = x + ctx @ wo^T + bo ; out = LayerNorm(y) * gamma + beta
// one block per (b,sq) row
// ---------------------------------------------------------------------------
__global__ __launch_bounds__(256) void out_kernel(
    const float* __restrict__ ctx,
    const float* __restrict__ x,
    const float* __restrict__ wo,
    const float* __restrict__ bo,
    const float* __restrict__ gamma,
    const float* __restrict__ beta,
    float* __restrict__ out)
{
    __shared__ float cs[HID];
    __shared__ float ys[HID];
    __shared__ float red[8];

    const int r = blockIdx.x;
    const int t = threadIdx.x;
    float4* cs4 = (float4*)cs;
    cs4[t] = ((const float4*)(ctx + (size_t)r * HID))[t];
    __syncthreads();

    float sum = 0.f, sumsq = 0.f;
    #pragma unroll
    for (int p = 0; p < 4; ++p) {
        const int j = t + p * 256;
        float a = bo[j] + x[(size_t)r * HID + j];
        const float4* wr = (const float4*)(wo + (size_t)j * HID);
        #pragma unroll 8
        for (int i = 0; i < HID / 4; ++i) {
            float4 wv = wr[i];
            float4 xv = cs4[i];
            a += wv.x * xv.x + wv.y * xv.y + wv.z * xv.z + wv.w * xv.w;
        }
        ys[j] = a;
        sum += a;
        sumsq += a * a;
    }

    #pragma unroll
    for (int off = 32; off; off >>= 1) {
        sum += __shfl_xor(sum, off);
        sumsq += __shfl_xor(sumsq, off);
    }
    const int w = t >> 6, l = t & 63;
    if (l == 0) { red[w] = sum; red[4 + w] = sumsq; }
    __syncthreads();
    sum = red[0] + red[1] + red[2] + red[3];
    sumsq = red[4] + red[5] + red[6] + red[7];
    const float mu = sum * (1.f / HID);
    const float var = sumsq * (1.f / HID) - mu * mu;
    const float rstd = rsqrtf(var + LN_EPS);

    #pragma unroll
    for (int p = 0; p < 4; ++p) {
        const int j = t + p * 256;
        out[(size_t)r * HID + j] = (ys[j] - mu) * rstd * gamma[j] + beta[j];
    }
}

// ---------------------------------------------------------------------------
extern "C" void kernel_launch(void* const* d_in, const int* in_sizes, int n_in,
                              void* d_out, int out_size, void* d_ws, size_t ws_size,
                              hipStream_t stream) {
    const float* x     = (const float*)d_in[0];
    const float* xm    = (const float*)d_in[1];
    const float* kc    = (const float*)d_in[2];
    const float* vc    = (const float*)d_in[3];
    const float* wq    = (const float*)d_in[4];
    const float* bq    = (const float*)d_in[5];
    const float* wo    = (const float*)d_in[6];
    const float* bo    = (const float*)d_in[7];
    const float* gamma = (const float*)d_in[8];
    const float* beta  = (const float*)d_in[9];
    float* out = (float*)d_out;

    float* ws = (float*)d_ws;
    float* q_ws   = ws;                                   // B*SQ*HID           = 65536
    float* o_ws   = q_ws + BATCH * SQ * HID;              // B*NH*NCHUNK*SQ*HD  = 1048576
    float* ml_ws  = o_ws + BATCH * NHEADS * NCHUNK * SQ * HD;  // B*NH*NCHUNK*SQ*2 = 32768
    float* ctx_ws = ml_ws + BATCH * NHEADS * NCHUNK * SQ * 2;  // B*SQ*HID       = 65536

    qrope_kernel<<<dim3(BATCH * SQ), 256, 0, stream>>>(x, xm, wq, bq, q_ws);
    attn_partial<<<dim3(NCHUNK, NHEADS, BATCH), 256, 0, stream>>>(q_ws, kc, vc, o_ws, ml_ws);
    attn_combine<<<dim3(BATCH * NHEADS), 256, 0, stream>>>(o_ws, ml_ws, ctx_ws);
    out_kernel<<<dim3(BATCH * SQ), 256, 0, stream>>>(ctx_ws, x, wo, bo, gamma, beta, out);
}

// Round 2
// 358.704 us; speedup vs baseline: 1.0975x; 1.0975x over previous
//
#include <hip/hip_runtime.h>
#include <math.h>

#define NHEADS 16
#define HD 64
#define HID 1024
#define BATCH 4
#define SQ 16
#define SKV 8192
#define NCHUNK 32
#define CHUNK 256   // keys per block
#define TK 64       // keys per LDS tile
#define NT (CHUNK / TK)
#define LN_EPS 1e-5f

// ---------------------------------------------------------------------------
// Kernel 1: q = RoPE(x @ wq^T + bq)  -> q_ws laid out [B][NH][SQ][HD]
// 2 rows per block, 1024 threads (thread t -> output col t)
// ---------------------------------------------------------------------------
__global__ __launch_bounds__(1024) void qrope_kernel(
    const float* __restrict__ x,     // [B*SQ][HID]
    const float* __restrict__ xm,    // [B*SQ][HD]
    const float* __restrict__ wq,    // [HID][HID]
    const float* __restrict__ bq,    // [HID]
    float* __restrict__ qout)        // [B][NH][SQ][HD]
{
    __shared__ float xs[2][HID];
    __shared__ float qrow[2][HID];
    __shared__ float xms[2][HD];

    const int r0 = blockIdx.x * 2;
    const int t = threadIdx.x;

    if (t < 512) {
        const int rr = t >> 8, i = t & 255;
        ((float4*)xs[rr])[i] = ((const float4*)(x + (size_t)(r0 + rr) * HID))[i];
    } else if (t < 544) {
        const int u = t - 512;           // 0..31
        const int rr = u >> 4, i = u & 15;
        ((float4*)xms[rr])[i] = ((const float4*)(xm + (size_t)(r0 + rr) * HD))[i];
    }
    __syncthreads();

    float a0 = bq[t], a1 = a0;
    const float4* wr = (const float4*)(wq + (size_t)t * HID);
    const float4* x0 = (const float4*)xs[0];
    const float4* x1 = (const float4*)xs[1];
    #pragma unroll 8
    for (int i = 0; i < HID / 4; ++i) {
        const float4 wv = wr[i];
        const float4 v0 = x0[i];
        const float4 v1 = x1[i];
        a0 += wv.x * v0.x + wv.y * v0.y + wv.z * v0.z + wv.w * v0.w;
        a1 += wv.x * v1.x + wv.y * v1.y + wv.z * v1.z + wv.w * v1.w;
    }
    qrow[0][t] = a0;
    qrow[1][t] = a1;
    __syncthreads();

    const int hh = t >> 6, dd = t & 63;
    #pragma unroll
    for (int rr = 0; rr < 2; ++rr) {
        const int r = r0 + rr, b = r >> 4, sq = r & 15;
        float v;
        if (dd < 32) {
            v = qrow[rr][hh * 64 + dd] * xms[rr][32 + dd]
              - qrow[rr][hh * 64 + dd + 32] * xms[rr][dd];
        } else {
            const int d2 = dd - 32;
            v = qrow[rr][hh * 64 + d2] * xms[rr][d2]
              + qrow[rr][hh * 64 + dd] * xms[rr][32 + d2];
        }
        qout[(((size_t)b * NHEADS + hh) * SQ + sq) * HD + dd] = v;
    }
}

// ---------------------------------------------------------------------------
// Kernel 2: flash-style partial attention.
// grid (NCHUNK, NH, B) = 2048 blocks, 256 threads (4 waves).
// wave w owns q rows 4w..4w+3; lane l = key-in-tile for QK, dim for PV.
// K staged in LDS (reg-prefetched); V read direct from global (coalesced).
// ---------------------------------------------------------------------------
__global__ __launch_bounds__(256) void attn_partial(
    const float* __restrict__ q,     // [B][NH][SQ][HD]
    const float* __restrict__ kc,    // [B][NH][SKV][HD]
    const float* __restrict__ vc,    // [B][NH][SKV][HD]
    float* __restrict__ o_part,      // [B*NH][NCHUNK][SQ][HD]
    float* __restrict__ ml_part)     // [B*NH][NCHUNK][SQ][2]
{
    __shared__ float4 Ks[TK * 17];   // [64 keys][16 f4 + 1 pad] stride 68 floats
    __shared__ float4 qs[SQ * 16];   // [16 q rows][16 float4]
    __shared__ float4 ps[SQ * 16];   // p values, [16 q rows][64 floats]

    const int chunk = blockIdx.x, h = blockIdx.y, b = blockIdx.z;
    const int bh = b * NHEADS + h;
    const int t = threadIdx.x, w = t >> 6, l = t & 63;

    const float* qb = q + (size_t)bh * SQ * HD;
    const float* kb = kc + (size_t)bh * SKV * HD + (size_t)chunk * CHUNK * HD;
    const float* vb = vc + (size_t)bh * SKV * HD + (size_t)chunk * CHUNK * HD;

    qs[t] = ((const float4*)qb)[t];  // full 16x64 q block

    float m[4], lsum[4], oacc[4];
    #pragma unroll
    for (int c = 0; c < 4; ++c) { m[c] = -INFINITY; lsum[c] = 0.f; oacc[c] = 0.f; }

    // prefetch K tile 0 into registers
    float4 kreg[4];
    {
        const float4* kg = (const float4*)kb;
        #pragma unroll
        for (int p = 0; p < 4; ++p) kreg[p] = kg[t + p * 256];
    }

    float* psf = (float*)ps;

    for (int tile = 0; tile < NT; ++tile) {
        __syncthreads();  // prior tile's readers done with Ks (also covers qs)
        #pragma unroll
        for (int p = 0; p < 4; ++p) {
            const int idx = t + p * 256;
            Ks[(idx >> 4) * 17 + (idx & 15)] = kreg[p];
        }
        __syncthreads();

        // issue next K tile's loads early (overlap with compute below)
        if (tile + 1 < NT) {
            const float4* kg = (const float4*)(kb + (size_t)(tile + 1) * TK * HD);
            #pragma unroll
            for (int p = 0; p < 4; ++p) kreg[p] = kg[t + p * 256];
        }

        // ---- scores: s[c] = q[4w+c] . K[key=l]
        float s[4] = {0.f, 0.f, 0.f, 0.f};
        #pragma unroll
        for (int j = 0; j < 16; ++j) {
            const float4 kv = Ks[l * 17 + j];
            #pragma unroll
            for (int c = 0; c < 4; ++c) {
                const float4 qv = qs[(4 * w + c) * 16 + j];
                s[c] += kv.x * qv.x + kv.y * qv.y + kv.z * qv.z + kv.w * qv.w;
            }
        }

        // ---- online softmax (rows wave-local, wave-wide reduce)
        #pragma unroll
        for (int c = 0; c < 4; ++c) {
            float mx = s[c];
            #pragma unroll
            for (int off = 32; off; off >>= 1) mx = fmaxf(mx, __shfl_xor(mx, off));
            const float mn = fmaxf(m[c], mx);
            const float p = __expf(s[c] - mn);
            float ssum = p;
            #pragma unroll
            for (int off = 32; off; off >>= 1) ssum += __shfl_xor(ssum, off);
            const float scale = __expf(m[c] - mn);
            lsum[c] = lsum[c] * scale + ssum;
            m[c] = mn;
            oacc[c] *= scale;
            psf[(4 * w + c) * 64 + l] = p;   // wave-local, no block sync
        }

        // ---- PV: V direct from global (coalesced per key row), p from LDS
        const float* vt = vb + (size_t)tile * TK * HD;
        #pragma unroll
        for (int kq = 0; kq < 16; ++kq) {
            const float v0 = vt[(kq * 4 + 0) * 64 + l];
            const float v1 = vt[(kq * 4 + 1) * 64 + l];
            const float v2 = vt[(kq * 4 + 2) * 64 + l];
            const float v3 = vt[(kq * 4 + 3) * 64 + l];
            #pragma unroll
            for (int c = 0; c < 4; ++c) {
                const float4 pq = ps[(4 * w + c) * 16 + kq];
                oacc[c] += pq.x * v0 + pq.y * v1 + pq.z * v2 + pq.w * v3;
            }
        }
    }

    // ---- write partials
    #pragma unroll
    for (int c = 0; c < 4; ++c) {
        const int qi = 4 * w + c;
        o_part[(((size_t)bh * NCHUNK + chunk) * SQ + qi) * HD + l] = oacc[c];
    }
    if (l == 0) {
        #pragma unroll
        for (int c = 0; c < 4; ++c) {
            const int qi = 4 * w + c;
            ml_part[(((size_t)bh * NCHUNK + chunk) * SQ + qi) * 2 + 0] = m[c];
            ml_part[(((size_t)bh * NCHUNK + chunk) * SQ + qi) * 2 + 1] = lsum[c];
        }
    }
}

// ---------------------------------------------------------------------------
// Kernel 3: combine partials over chunks -> ctx [B][SQ][HID]
// one block per (b,h), 256 threads
// ---------------------------------------------------------------------------
__global__ __launch_bounds__(256) void attn_combine(
    const float* __restrict__ o_part,
    const float* __restrict__ ml_part,
    float* __restrict__ ctx)
{
    __shared__ float mls[NCHUNK * SQ * 2];   // 1024 floats
    const int bh = blockIdx.x;
    const int b = bh >> 4, h = bh & 15;
    const int t = threadIdx.x;

    #pragma unroll
    for (int p = 0; p < 4; ++p)
        mls[t + p * 256] = ml_part[(size_t)bh * NCHUNK * SQ * 2 + t + p * 256];
    __syncthreads();

    const int d = t & 63, qg = t >> 6;
    #pragma unroll
    for (int ii = 0; ii < 4; ++ii) {
        const int qi = qg * 4 + ii;
        float M = -INFINITY;
        #pragma unroll
        for (int c = 0; c < NCHUNK; ++c) M = fmaxf(M, mls[(c * SQ + qi) * 2]);
        float L = 0.f, O = 0.f;
        #pragma unroll
        for (int c = 0; c < NCHUNK; ++c) {
            const float sc = __expf(mls[(c * SQ + qi) * 2] - M);
            L += mls[(c * SQ + qi) * 2 + 1] * sc;
            O += o_part[(((size_t)bh * NCHUNK + c) * SQ + qi) * HD + d] * sc;
        }
        ctx[((size_t)b * SQ + qi) * HID + h * HD + d] = O / L;
    }
}

// ---------------------------------------------------------------------------
// Kernel 4: y = x + ctx @ wo^T + bo ; out = LN(y) * gamma + beta
// 2 rows per block, 1024 threads (thread t -> col t, both rows)
// ---------------------------------------------------------------------------
__global__ __launch_bounds__(1024) void out_kernel(
    const float* __restrict__ ctx,
    const float* __restrict__ x,
    const float* __restrict__ wo,
    const float* __restrict__ bo,
    const float* __restrict__ gamma,
    const float* __restrict__ beta,
    float* __restrict__ out)
{
    __shared__ float cs[2][HID];
    __shared__ float red[2][2][16];  // [row][sum|sumsq][wave]

    const int r0 = blockIdx.x * 2;
    const int t = threadIdx.x;

    if (t < 512) {
        const int rr = t >> 8, i = t & 255;
        ((float4*)cs[rr])[i] = ((const float4*)(ctx + (size_t)(r0 + rr) * HID))[i];
    }
    __syncthreads();

    float a0 = bo[t] + x[(size_t)r0 * HID + t];
    float a1 = bo[t] + x[(size_t)(r0 + 1) * HID + t];
    const float4* wr = (const float4*)(wo + (size_t)t * HID);
    const float4* c0 = (const float4*)cs[0];
    const float4* c1 = (const float4*)cs[1];
    #pragma unroll 8
    for (int i = 0; i < HID / 4; ++i) {
        const float4 wv = wr[i];
        const float4 v0 = c0[i];
        const float4 v1 = c1[i];
        a0 += wv.x * v0.x + wv.y * v0.y + wv.z * v0.z + wv.w * v0.w;
        a1 += wv.x * v1.x + wv.y * v1.y + wv.z * v1.z + wv.w * v1.w;
    }

    float s0 = a0, q0 = a0 * a0, s1 = a1, q1 = a1 * a1;
    #pragma unroll
    for (int off = 32; off; off >>= 1) {
        s0 += __shfl_xor(s0, off);
        q0 += __shfl_xor(q0, off);
        s1 += __shfl_xor(s1, off);
        q1 += __shfl_xor(q1, off);
    }
    const int w = t >> 6, l = t & 63;
    if (l == 0) {
        red[0][0][w] = s0; red[0][1][w] = q0;
        red[1][0][w] = s1; red[1][1][w] = q1;
    }
    __syncthreads();
    float sum0 = 0.f, ss0 = 0.f, sum1 = 0.f, ss1 = 0.f;
    #pragma unroll
    for (int i = 0; i < 16; ++i) {
        sum0 += red[0][0][i]; ss0 += red[0][1][i];
        sum1 += red[1][0][i]; ss1 += red[1][1][i];
    }
    const float mu0 = sum0 * (1.f / HID);
    const float var0 = ss0 * (1.f / HID) - mu0 * mu0;
    const float rstd0 = rsqrtf(var0 + LN_EPS);
    const float mu1 = sum1 * (1.f / HID);
    const float var1 = ss1 * (1.f / HID) - mu1 * mu1;
    const float rstd1 = rsqrtf(var1 + LN_EPS);

    const float g = gamma[t], be = beta[t];
    out[(size_t)r0 * HID + t] = (a0 - mu0) * rstd0 * g + be;
    out[(size_t)(r0 + 1) * HID + t] = (a1 - mu1) * rstd1 * g + be;
}

// ---------------------------------------------------------------------------
extern "C" void kernel_launch(void* const* d_in, const int* in_sizes, int n_in,
                              void* d_out, int out_size, void* d_ws, size_t ws_size,
                              hipStream_t stream) {
    const float* x     = (const float*)d_in[0];
    const float* xm    = (const float*)d_in[1];
    const float* kc    = (const float*)d_in[2];
    const float* vc    = (const float*)d_in[3];
    const float* wq    = (const float*)d_in[4];
    const float* bq    = (const float*)d_in[5];
    const float* wo    = (const float*)d_in[6];
    const float* bo    = (const float*)d_in[7];
    const float* gamma = (const float*)d_in[8];
    const float* beta  = (const float*)d_in[9];
    float* out = (float*)d_out;

    float* ws = (float*)d_ws;
    float* q_ws   = ws;                                        // 65536
    float* o_ws   = q_ws + BATCH * SQ * HID;                   // 2097152
    float* ml_ws  = o_ws + (size_t)BATCH * NHEADS * NCHUNK * SQ * HD;  // 65536
    float* ctx_ws = ml_ws + BATCH * NHEADS * NCHUNK * SQ * 2;  // 65536

    qrope_kernel<<<dim3(BATCH * SQ / 2), 1024, 0, stream>>>(x, xm, wq, bq, q_ws);
    attn_partial<<<dim3(NCHUNK, NHEADS, BATCH), 256, 0, stream>>>(q_ws, kc, vc, o_ws, ml_ws);
    attn_combine<<<dim3(BATCH * NHEADS), 256, 0, stream>>>(o_ws, ml_ws, ctx_ws);
    out_kernel<<<dim3(BATCH * SQ / 2), 1024, 0, stream>>>(ctx_ws, x, wo, bo, gamma, beta, out);
}

// Round 3
// 171.747 us; speedup vs baseline: 2.2922x; 2.0886x over previous
//
#include <hip/hip_runtime.h>
#include <math.h>

#define NHEADS 16
#define HD 64
#define HID 1024
#define BATCH 4
#define SQ 16
#define SKV 8192
#define ROWS 64     // B*SQ
#define NCHUNK 32
#define CHUNK 256   // keys per attn block
#define TK 64       // keys per LDS tile
#define NT (CHUNK / TK)
#define LN_EPS 1e-5f

// ---------------------------------------------------------------------------
// Kernel 1: q = RoPE(x @ wq^T + bq) -> [B][NH][SQ][HD]
// Wave-per-output-column GEMV. 256 blocks x 256 threads (4 waves).
// Block cb: head h = cb>>4, sub = cb&15; waves own cols
//   {64h + 2sub, 64h + 2sub+1, 64h + 2sub+32, 64h + 2sub+33}
// so RoPE pairs (dd, dd+32) live in the same block.
// Lanes split K; x staged in LDS in 4 chunks of 256.
// ---------------------------------------------------------------------------
__global__ __launch_bounds__(256) void qrope_gemv(
    const float* __restrict__ x,     // [64][1024]
    const float* __restrict__ xm,    // [64][64]
    const float* __restrict__ wq,    // [1024][1024]
    const float* __restrict__ bq,    // [1024]
    float* __restrict__ qout)        // [B][NH][SQ][HD]
{
    __shared__ float xs[ROWS * 256];   // 64 KB chunk buffer
    __shared__ float sqx[4][ROWS];     // rope exchange

    const int t = threadIdx.x, w = t >> 6, l = t & 63;
    const int cb = blockIdx.x;
    const int h = cb >> 4;
    const int sub = cb & 15;
    const int dd = sub * 2 + (w & 1) + (w >> 1) * 32;   // 0..63
    const int j = h * 64 + dd;                          // output column

    float acc[ROWS];
    #pragma unroll
    for (int r = 0; r < ROWS; ++r) acc[r] = 0.f;

    const float4* x4 = (const float4*)x;
    const float4* w4 = (const float4*)(wq + (size_t)j * HID);
    float4* xs4 = (float4*)xs;

    for (int ck = 0; ck < 4; ++ck) {
        __syncthreads();
        // stage x[:, ck*256:(ck+1)*256] -> xs[64][256] (coalesced)
        #pragma unroll
        for (int p = 0; p < 16; ++p) {
            const int idx = t + p * 256;        // 0..4095 = r*64 + c
            const int r = idx >> 6, c = idx & 63;
            xs4[idx] = x4[(size_t)r * 256 + ck * 64 + c];
        }
        __syncthreads();

        const float4 wf = w4[ck * 64 + l];      // coalesced 1KB per wave
        #pragma unroll
        for (int r = 0; r < ROWS; ++r) {
            const float4 xf = xs4[r * 64 + l];  // contiguous across lanes
            acc[r] += wf.x * xf.x + wf.y * xf.y + wf.z * xf.z + wf.w * xf.w;
        }
    }

    // butterfly-reduce each row's partial across the 64 lanes
    #pragma unroll
    for (int r = 0; r < ROWS; ++r) {
        float a = acc[r];
        #pragma unroll
        for (int off = 32; off; off >>= 1) a += __shfl_xor(a, off);
        acc[r] = a;
    }
    // lane l keeps row l (compile-time select chain)
    float val = acc[0];
    #pragma unroll
    for (int r = 1; r < ROWS; ++r) val = (l == r) ? acc[r] : val;
    val += bq[j];

    sqx[w][l] = val;
    __syncthreads();

    // RoPE: sin = xm[r][0:32], cos = xm[r][32:64]
    const int r = l;   // row = b*16+sq
    float outv;
    if (w < 2) {
        const float q0 = sqx[w][l];
        const float q1 = sqx[w + 2][l];
        const float sn = xm[r * 64 + dd];
        const float co = xm[r * 64 + 32 + dd];
        outv = q0 * co - q1 * sn;
    } else {
        const int d2 = dd - 32;
        const float q0 = sqx[w - 2][l];
        const float q1 = sqx[w][l];
        const float sn = xm[r * 64 + d2];
        const float co = xm[r * 64 + 32 + d2];
        outv = q0 * sn + q1 * co;
    }
    const int b = r >> 4, s_ = r & 15;
    qout[(((size_t)b * NHEADS + h) * SQ + s_) * HD + dd] = outv;
}

// ---------------------------------------------------------------------------
// Kernel 2: flash-style partial attention (unchanged from round 2).
// grid (NCHUNK, NH, B) = 2048 blocks, 256 threads (4 waves).
// ---------------------------------------------------------------------------
__global__ __launch_bounds__(256) void attn_partial(
    const float* __restrict__ q,     // [B][NH][SQ][HD]
    const float* __restrict__ kc,    // [B][NH][SKV][HD]
    const float* __restrict__ vc,    // [B][NH][SKV][HD]
    float* __restrict__ o_part,      // [B*NH][NCHUNK][SQ][HD]
    float* __restrict__ ml_part)     // [B*NH][NCHUNK][SQ][2]
{
    __shared__ float4 Ks[TK * 17];
    __shared__ float4 qs[SQ * 16];
    __shared__ float4 ps[SQ * 16];

    const int chunk = blockIdx.x, h = blockIdx.y, b = blockIdx.z;
    const int bh = b * NHEADS + h;
    const int t = threadIdx.x, w = t >> 6, l = t & 63;

    const float* qb = q + (size_t)bh * SQ * HD;
    const float* kb = kc + (size_t)bh * SKV * HD + (size_t)chunk * CHUNK * HD;
    const float* vb = vc + (size_t)bh * SKV * HD + (size_t)chunk * CHUNK * HD;

    qs[t] = ((const float4*)qb)[t];

    float m[4], lsum[4], oacc[4];
    #pragma unroll
    for (int c = 0; c < 4; ++c) { m[c] = -INFINITY; lsum[c] = 0.f; oacc[c] = 0.f; }

    float4 kreg[4];
    {
        const float4* kg = (const float4*)kb;
        #pragma unroll
        for (int p = 0; p < 4; ++p) kreg[p] = kg[t + p * 256];
    }

    float* psf = (float*)ps;

    for (int tile = 0; tile < NT; ++tile) {
        __syncthreads();
        #pragma unroll
        for (int p = 0; p < 4; ++p) {
            const int idx = t + p * 256;
            Ks[(idx >> 4) * 17 + (idx & 15)] = kreg[p];
        }
        __syncthreads();

        if (tile + 1 < NT) {
            const float4* kg = (const float4*)(kb + (size_t)(tile + 1) * TK * HD);
            #pragma unroll
            for (int p = 0; p < 4; ++p) kreg[p] = kg[t + p * 256];
        }

        float s[4] = {0.f, 0.f, 0.f, 0.f};
        #pragma unroll
        for (int j = 0; j < 16; ++j) {
            const float4 kv = Ks[l * 17 + j];
            #pragma unroll
            for (int c = 0; c < 4; ++c) {
                const float4 qv = qs[(4 * w + c) * 16 + j];
                s[c] += kv.x * qv.x + kv.y * qv.y + kv.z * qv.z + kv.w * qv.w;
            }
        }

        #pragma unroll
        for (int c = 0; c < 4; ++c) {
            float mx = s[c];
            #pragma unroll
            for (int off = 32; off; off >>= 1) mx = fmaxf(mx, __shfl_xor(mx, off));
            const float mn = fmaxf(m[c], mx);
            const float p = __expf(s[c] - mn);
            float ssum = p;
            #pragma unroll
            for (int off = 32; off; off >>= 1) ssum += __shfl_xor(ssum, off);
            const float scale = __expf(m[c] - mn);
            lsum[c] = lsum[c] * scale + ssum;
            m[c] = mn;
            oacc[c] *= scale;
            psf[(4 * w + c) * 64 + l] = p;
        }

        const float* vt = vb + (size_t)tile * TK * HD;
        #pragma unroll
        for (int kq = 0; kq < 16; ++kq) {
            const float v0 = vt[(kq * 4 + 0) * 64 + l];
            const float v1 = vt[(kq * 4 + 1) * 64 + l];
            const float v2 = vt[(kq * 4 + 2) * 64 + l];
            const float v3 = vt[(kq * 4 + 3) * 64 + l];
            #pragma unroll
            for (int c = 0; c < 4; ++c) {
                const float4 pq = ps[(4 * w + c) * 16 + kq];
                oacc[c] += pq.x * v0 + pq.y * v1 + pq.z * v2 + pq.w * v3;
            }
        }
    }

    #pragma unroll
    for (int c = 0; c < 4; ++c) {
        const int qi = 4 * w + c;
        o_part[(((size_t)bh * NCHUNK + chunk) * SQ + qi) * HD + l] = oacc[c];
    }
    if (l == 0) {
        #pragma unroll
        for (int c = 0; c < 4; ++c) {
            const int qi = 4 * w + c;
            ml_part[(((size_t)bh * NCHUNK + chunk) * SQ + qi) * 2 + 0] = m[c];
            ml_part[(((size_t)bh * NCHUNK + chunk) * SQ + qi) * 2 + 1] = lsum[c];
        }
    }
}

// ---------------------------------------------------------------------------
// Kernel 3: combine partials -> ctx [64][1024]
// 256 blocks: block = (bh, qgroup of 4 rows); thread = (qi_local, d)
// ---------------------------------------------------------------------------
__global__ __launch_bounds__(256) void attn_combine(
    const float* __restrict__ o_part,
    const float* __restrict__ ml_part,
    float* __restrict__ ctx)
{
    __shared__ float mls[NCHUNK * 4 * 2];   // 256 floats
    const int bh = blockIdx.x >> 2, qg = blockIdx.x & 3;
    const int b = bh >> 4, h = bh & 15;
    const int t = threadIdx.x;
    const int qi_l = t >> 6, d = t & 63;
    const int qi = qg * 4 + qi_l;

    // stage m,l for this block's 4 q-rows: t = (c<<3)|(qi_l<<1)|comp
    mls[t] = ml_part[(((size_t)bh * NCHUNK + (t >> 3)) * SQ + qg * 4 + ((t >> 1) & 3)) * 2 + (t & 1)];
    __syncthreads();

    float M = -INFINITY;
    #pragma unroll
    for (int c = 0; c < NCHUNK; ++c) M = fmaxf(M, mls[(c * 4 + qi_l) * 2]);
    float L = 0.f, O = 0.f;
    #pragma unroll 4
    for (int c = 0; c < NCHUNK; ++c) {
        const float sc = __expf(mls[(c * 4 + qi_l) * 2] - M);
        L += mls[(c * 4 + qi_l) * 2 + 1] * sc;
        O += o_part[(((size_t)bh * NCHUNK + c) * SQ + qi) * HD + d] * sc;
    }
    ctx[((size_t)(b * SQ + qi)) * HID + h * HD + d] = O / L;
}

// ---------------------------------------------------------------------------
// Kernel 4: y = x + ctx @ wo^T + bo   (wave-per-column GEMV, same as kernel 1)
// 256 blocks x 256 threads; wave w owns column j = 4*blockIdx + w
// ---------------------------------------------------------------------------
__global__ __launch_bounds__(256) void out_gemv(
    const float* __restrict__ ctx,   // [64][1024]
    const float* __restrict__ x,     // [64][1024]
    const float* __restrict__ wo,    // [1024][1024]
    const float* __restrict__ bo,
    float* __restrict__ y)           // [64][1024]
{
    __shared__ float xs[ROWS * 256];

    const int t = threadIdx.x, w = t >> 6, l = t & 63;
    const int j = blockIdx.x * 4 + w;

    float acc[ROWS];
    #pragma unroll
    for (int r = 0; r < ROWS; ++r) acc[r] = 0.f;

    const float4* c4 = (const float4*)ctx;
    const float4* w4 = (const float4*)(wo + (size_t)j * HID);
    float4* xs4 = (float4*)xs;

    for (int ck = 0; ck < 4; ++ck) {
        __syncthreads();
        #pragma unroll
        for (int p = 0; p < 16; ++p) {
            const int idx = t + p * 256;
            const int r = idx >> 6, c = idx & 63;
            xs4[idx] = c4[(size_t)r * 256 + ck * 64 + c];
        }
        __syncthreads();

        const float4 wf = w4[ck * 64 + l];
        #pragma unroll
        for (int r = 0; r < ROWS; ++r) {
            const float4 xf = xs4[r * 64 + l];
            acc[r] += wf.x * xf.x + wf.y * xf.y + wf.z * xf.z + wf.w * xf.w;
        }
    }

    #pragma unroll
    for (int r = 0; r < ROWS; ++r) {
        float a = acc[r];
        #pragma unroll
        for (int off = 32; off; off >>= 1) a += __shfl_xor(a, off);
        acc[r] = a;
    }
    float val = acc[0];
    #pragma unroll
    for (int r = 1; r < ROWS; ++r) val = (l == r) ? acc[r] : val;

    val += bo[j] + x[(size_t)l * HID + j];
    y[(size_t)l * HID + j] = val;
}

// ---------------------------------------------------------------------------
// Kernel 5: out = LN(y) * gamma + beta ; one block per row
// ---------------------------------------------------------------------------
__global__ __launch_bounds__(256) void ln_kernel(
    const float* __restrict__ y,
    const float* __restrict__ gamma,
    const float* __restrict__ beta,
    float* __restrict__ out)
{
    __shared__ float red[8];
    const int r = blockIdx.x, t = threadIdx.x;
    const int w = t >> 6, l = t & 63;

    const float4 yv = ((const float4*)(y + (size_t)r * HID))[t];
    float sum = yv.x + yv.y + yv.z + yv.w;
    float ssq = yv.x * yv.x + yv.y * yv.y + yv.z * yv.z + yv.w * yv.w;
    #pragma unroll
    for (int off = 32; off; off >>= 1) {
        sum += __shfl_xor(sum, off);
        ssq += __shfl_xor(ssq, off);
    }
    if (l == 0) { red[w] = sum; red[4 + w] = ssq; }
    __syncthreads();
    sum = red[0] + red[1] + red[2] + red[3];
    ssq = red[4] + red[5] + red[6] + red[7];
    const float mu = sum * (1.f / HID);
    const float var = ssq * (1.f / HID) - mu * mu;
    const float rstd = rsqrtf(var + LN_EPS);

    const float4 g = ((const float4*)gamma)[t];
    const float4 be = ((const float4*)beta)[t];
    float4 o;
    o.x = (yv.x - mu) * rstd * g.x + be.x;
    o.y = (yv.y - mu) * rstd * g.y + be.y;
    o.z = (yv.z - mu) * rstd * g.z + be.z;
    o.w = (yv.w - mu) * rstd * g.w + be.w;
    ((float4*)(out + (size_t)r * HID))[t] = o;
}

// ---------------------------------------------------------------------------
extern "C" void kernel_launch(void* const* d_in, const int* in_sizes, int n_in,
                              void* d_out, int out_size, void* d_ws, size_t ws_size,
                              hipStream_t stream) {
    const float* x     = (const float*)d_in[0];
    const float* xm    = (const float*)d_in[1];
    const float* kc    = (const float*)d_in[2];
    const float* vc    = (const float*)d_in[3];
    const float* wq    = (const float*)d_in[4];
    const float* bq    = (const float*)d_in[5];
    const float* wo    = (const float*)d_in[6];
    const float* bo    = (const float*)d_in[7];
    const float* gamma = (const float*)d_in[8];
    const float* beta  = (const float*)d_in[9];
    float* out = (float*)d_out;

    float* ws = (float*)d_ws;
    float* q_ws   = ws;                                               // 65536
    float* o_ws   = q_ws + ROWS * HID;                                // 2097152
    float* ml_ws  = o_ws + (size_t)BATCH * NHEADS * NCHUNK * SQ * HD; // 65536
    float* ctx_ws = ml_ws + BATCH * NHEADS * NCHUNK * SQ * 2;         // 65536
    float* y_ws   = ctx_ws + ROWS * HID;                              // 65536

    qrope_gemv<<<dim3(256), 256, 0, stream>>>(x, xm, wq, bq, q_ws);
    attn_partial<<<dim3(NCHUNK, NHEADS, BATCH), 256, 0, stream>>>(q_ws, kc, vc, o_ws, ml_ws);
    attn_combine<<<dim3(256), 256, 0, stream>>>(o_ws, ml_ws, ctx_ws);
    out_gemv<<<dim3(256), 256, 0, stream>>>(ctx_ws, x, wo, bo, y_ws);
    ln_kernel<<<dim3(ROWS), 256, 0, stream>>>(y_ws, gamma, beta, out);
}